// Round 1
// baseline (719.678 us; speedup 1.0000x reference)
//
#include <hip/hip_runtime.h>

// SMPL body model forward: fp32 baseline, multi-kernel pipeline.
// Stages: [pre: SJ/Jt precompute] [scale] [J joints] [FK] [pose GEMM + shape fuse]
//         [LBS in-place] [keypoint regression with atomics]

constexpr int N   = 512;
constexpr int V   = 6890;
constexpr int V3  = V * 3;        // 20670
constexpr int NJ  = 24;
constexpr int NB  = 10;
constexpr int NP  = 207;
constexpr int NK  = 95;           // 25 body + 70 face keypoints

// workspace layout (float offsets)
constexpr size_t VP_OFF    = 0;                               // v_posed -> verts (in place), N*V3
constexpr size_t SCALE_OFF = (size_t)N * V3;                  // N
constexpr size_t SJ_OFF    = SCALE_OFF + N;                   // NB*72
constexpr size_t JT_OFF    = SJ_OFF + (size_t)NB * 72;        // 72
constexpr size_t J_OFF     = JT_OFF + 72;                     // N*72
constexpr size_t A_OFF     = J_OFF + (size_t)N * 72;          // N*288 (3x4 rows per joint)

// ---------------------------------------------------------------------------
// SJ[k][j][c] = sum_v shapedirs[k, v*3+c] * Jreg[j,v];  Jt[j][c] = sum_v vt[v*3+c]*Jreg[j,v]
// batch-independent; one block per (j,c)
__global__ __launch_bounds__(256) void k_pre(const float* __restrict__ jreg,
                                             const float* __restrict__ sd,
                                             const float* __restrict__ vt,
                                             float* __restrict__ ws) {
    int jc = blockIdx.x;                 // 0..71
    int j = jc / 3, c = jc % 3;
    int tid = threadIdx.x;
    float acc[NB + 1];
#pragma unroll
    for (int t = 0; t <= NB; ++t) acc[t] = 0.f;
    for (int v = tid; v < V; v += 256) {
        float w = jreg[(size_t)j * V + v];
        int col = v * 3 + c;
#pragma unroll
        for (int k = 0; k < NB; ++k) acc[k] += w * sd[(size_t)k * V3 + col];
        acc[NB] += w * vt[col];
    }
    __shared__ float red[256];
    for (int t = 0; t <= NB; ++t) {
        red[tid] = acc[t];
        __syncthreads();
        for (int s = 128; s > 0; s >>= 1) {
            if (tid < s) red[tid] += red[tid + s];
            __syncthreads();
        }
        if (tid == 0) {
            if (t < NB) ws[SJ_OFF + (size_t)t * 72 + jc] = red[0];
            else        ws[JT_OFF + jc] = red[0];
        }
        __syncthreads();
    }
}

// ---------------------------------------------------------------------------
// scale[n] = 1.66 / (vss[2802,1] + vss[6262,1] - vss[2237,1] - vss[6728,1])
__global__ __launch_bounds__(256) void k_scale(const float* __restrict__ betas,
                                               const float* __restrict__ vt,
                                               const float* __restrict__ sd,
                                               float* __restrict__ ws) {
    int n = blockIdx.x * 256 + threadIdx.x;
    if (n >= N) return;
    const int idx[4] = {2802 * 3 + 1, 6262 * 3 + 1, 2237 * 3 + 1, 6728 * 3 + 1};
    float b[NB];
#pragma unroll
    for (int k = 0; k < NB; ++k) b[k] = betas[n * NB + k];
    float vals[4];
#pragma unroll
    for (int t = 0; t < 4; ++t) {
        float a = vt[idx[t]];
#pragma unroll
        for (int k = 0; k < NB; ++k) a += b[k] * sd[(size_t)k * V3 + idx[t]];
        vals[t] = a;
    }
    float h = vals[0] + vals[1] - vals[2] - vals[3];
    ws[SCALE_OFF + n] = 1.66f / h;
}

// ---------------------------------------------------------------------------
// J[n,jc] = scale[n] * (sum_k betas[n,k]*SJ[k,jc] + Jt[jc])
__global__ __launch_bounds__(256) void k_joints(const float* __restrict__ betas,
                                                float* __restrict__ ws) {
    int t = blockIdx.x * 256 + threadIdx.x;
    if (t >= N * 72) return;
    int n = t / 72, jc = t - n * 72;
    float a = ws[JT_OFF + jc];
#pragma unroll
    for (int k = 0; k < NB; ++k) a += betas[n * NB + k] * ws[SJ_OFF + (size_t)k * 72 + jc];
    ws[J_OFF + t] = ws[SCALE_OFF + n] * a;
}

// ---------------------------------------------------------------------------
// FK: one block (1 wave) per batch item. G[j] = 3x4 global transform.
// A[n,j] = [Rg | tg - Rg @ J_j]   (3x4, row-major, 12 floats per joint)
__global__ __launch_bounds__(64) void k_fk(const float* __restrict__ pose,
                                           float* __restrict__ ws) {
    int n = blockIdx.x;
    int tid = threadIdx.x;
    __shared__ float G[NJ * 12];
    __shared__ float Jl[NJ * 3];
    for (int e = tid; e < 72; e += 64) Jl[e] = ws[J_OFF + (size_t)n * 72 + e];
    __syncthreads();
    const int par[NJ] = {0,0,0,0,1,2,3,4,5,6,7,8,9,9,9,12,13,14,16,17,18,19,20,21};
    // root
    if (tid < 12) {
        int r = tid >> 2, c = tid & 3;
        G[tid] = (c < 3) ? pose[(size_t)n * 216 + r * 3 + c] : Jl[r];
    }
    __syncthreads();
    for (int i = 1; i < NJ; ++i) {
        int p = par[i];
        if (tid < 12) {
            int r = tid >> 2, c = tid & 3;
            const float* gp = &G[p * 12 + r * 4];
            float v;
            if (c < 3) {
                const float* Ri = pose + (size_t)n * 216 + i * 9;
                v = gp[0] * Ri[0 * 3 + c] + gp[1] * Ri[1 * 3 + c] + gp[2] * Ri[2 * 3 + c];
            } else {
                float t0 = Jl[i * 3 + 0] - Jl[p * 3 + 0];
                float t1 = Jl[i * 3 + 1] - Jl[p * 3 + 1];
                float t2 = Jl[i * 3 + 2] - Jl[p * 3 + 2];
                v = gp[0] * t0 + gp[1] * t1 + gp[2] * t2 + gp[3];
            }
            G[i * 12 + tid] = v;
        }
        __syncthreads();
    }
    for (int idx = tid; idx < 288; idx += 64) {
        int j = idx / 12, rc = idx - j * 12;
        int r = rc >> 2, c = rc & 3;
        float v;
        if (c < 3) v = G[j * 12 + rc];
        else {
            const float* g = &G[j * 12 + r * 4];
            v = g[3] - (g[0] * Jl[j * 3 + 0] + g[1] * Jl[j * 3 + 1] + g[2] * Jl[j * 3 + 2]);
        }
        ws[A_OFF + (size_t)n * 288 + idx] = v;
    }
}

// ---------------------------------------------------------------------------
// v_posed[n,i] = pose_feature[n,:] @ posedirs[:,i] + scale[n]*(betas[n,:]@shapedirs[:,i] + vt[i])
// block: 16 batch rows x 1024 cols (4 cols/thread), K=207 in LDS
__global__ __launch_bounds__(256) void k_posegemm(const float* __restrict__ pose,
                                                  const float* __restrict__ betas,
                                                  const float* __restrict__ vt,
                                                  const float* __restrict__ sd,
                                                  const float* __restrict__ pdirs,
                                                  float* __restrict__ ws) {
    __shared__ float pf[16 * 208];   // pose_feature, padded row
    __shared__ float bs[16 * NB];
    __shared__ float ss[16];
    int tid = threadIdx.x;
    int n0 = blockIdx.y * 16;
    int c0 = blockIdx.x * 1024;
    for (int e = tid; e < 16 * NP; e += 256) {
        int nn = e / NP, k = e - nn * NP;
        float v = pose[(size_t)(n0 + nn) * 216 + 9 + k];
        int km = k % 9;
        if (km == 0 || km == 4 || km == 8) v -= 1.f;
        pf[nn * 208 + k] = v;
    }
    if (tid < 16 * NB) bs[tid] = betas[n0 * NB + tid];
    if (tid < 16) ss[tid] = ws[SCALE_OFF + n0 + tid];
    __syncthreads();

    int col[4];
#pragma unroll
    for (int q = 0; q < 4; ++q) {
        int i = c0 + tid + 256 * q;
        col[q] = (i < V3) ? i : (V3 - 1);   // clamp for loads; store is guarded
    }
    float acc[16][4];
#pragma unroll
    for (int nn = 0; nn < 16; ++nn)
#pragma unroll
        for (int q = 0; q < 4; ++q) acc[nn][q] = 0.f;

    for (int k4 = 0; k4 < 51; ++k4) {      // k = 0..203
        float b[4][4];
#pragma unroll
        for (int kk = 0; kk < 4; ++kk) {
            const float* row = pdirs + (size_t)(k4 * 4 + kk) * V3;
#pragma unroll
            for (int q = 0; q < 4; ++q) b[kk][q] = row[col[q]];
        }
#pragma unroll
        for (int nn = 0; nn < 16; ++nn) {
            float4 p = *reinterpret_cast<const float4*>(&pf[nn * 208 + k4 * 4]);
#pragma unroll
            for (int q = 0; q < 4; ++q)
                acc[nn][q] += p.x * b[0][q] + p.y * b[1][q] + p.z * b[2][q] + p.w * b[3][q];
        }
    }
    for (int k = 204; k < NP; ++k) {       // tail
        float b[4];
        const float* row = pdirs + (size_t)k * V3;
#pragma unroll
        for (int q = 0; q < 4; ++q) b[q] = row[col[q]];
#pragma unroll
        for (int nn = 0; nn < 16; ++nn) {
            float p = pf[nn * 208 + k];
#pragma unroll
            for (int q = 0; q < 4; ++q) acc[nn][q] += p * b[q];
        }
    }
    // epilogue: add scale*(betas@shapedirs + v_template), store
#pragma unroll
    for (int q = 0; q < 4; ++q) {
        int i = c0 + tid + 256 * q;
        if (i >= V3) continue;
        float sdq[NB];
#pragma unroll
        for (int k = 0; k < NB; ++k) sdq[k] = sd[(size_t)k * V3 + i];
        float vti = vt[i];
        for (int nn = 0; nn < 16; ++nn) {
            float sdot = vti;
#pragma unroll
            for (int k = 0; k < NB; ++k) sdot += bs[nn * NB + k] * sdq[k];
            ws[VP_OFF + (size_t)(n0 + nn) * V3 + i] = acc[nn][q] + ss[nn] * sdot;
        }
    }
}

// ---------------------------------------------------------------------------
// LBS: T = sum_j w[v,j] A[n,j]; vert = T(3x4) @ [vp;1] + trans. In place over vp.
// A[n] read with block-uniform addresses -> compiler scalarizes to s_load.
__global__ __launch_bounds__(256) void k_lbs(const float* __restrict__ lbsw,
                                             const float* __restrict__ trans,
                                             float* __restrict__ ws) {
    __shared__ float wl[256 * 25];
    int tid = threadIdx.x;
    int n = blockIdx.y;
    int v0 = blockIdx.x * 256;
    for (int e = tid; e < 256 * 24; e += 256) {
        int g = v0 * 24 + e;
        float val = (g < V * 24) ? lbsw[g] : 0.f;
        int vv = e / 24, j = e - vv * 24;
        wl[vv * 25 + j] = val;
    }
    __syncthreads();
    int v = v0 + tid;
    if (v >= V) return;
    const float* An = ws + A_OFF + (size_t)n * 288;
    size_t vp_idx = VP_OFF + (size_t)n * V3 + (size_t)v * 3;
    float p0 = ws[vp_idx + 0], p1 = ws[vp_idx + 1], p2 = ws[vp_idx + 2];
    float T[12];
#pragma unroll
    for (int e = 0; e < 12; ++e) T[e] = 0.f;
    for (int j = 0; j < NJ; ++j) {
        float w = wl[tid * 25 + j];
#pragma unroll
        for (int e = 0; e < 12; ++e) T[e] += w * An[j * 12 + e];
    }
    float x = T[0] * p0 + T[1] * p1 + T[2]  * p2 + T[3]  + trans[n * 3 + 0];
    float y = T[4] * p0 + T[5] * p1 + T[6]  * p2 + T[7]  + trans[n * 3 + 1];
    float z = T[8] * p0 + T[9] * p1 + T[10] * p2 + T[11] + trans[n * 3 + 2];
    ws[vp_idx + 0] = x;
    ws[vp_idx + 1] = y;
    ws[vp_idx + 2] = z;
}

// ---------------------------------------------------------------------------
// out[n,k,c] = sum_v reg[k,v] * verts[n,v,c].  Block: 32 k x 128 n, v-chunk of 288.
// thread: 4k x 4n register tile; LDS tiles padded for conflict-free b128 reads.
__global__ __launch_bounds__(256) void k_reg(const float* __restrict__ b25,
                                             const float* __restrict__ face,
                                             const float* __restrict__ ws,
                                             float* __restrict__ out) {
    __shared__ float rs[32 * 36];        // reg tile  [32 k][32 v] pad 36
    __shared__ float vs[128 * 108];      // verts tile [128 n][3 c][32 v] pad 36
    int tid = threadIdx.x;
    int kq = tid & 7, nq = tid >> 3;     // kq 0..7, nq 0..31
    int k0 = blockIdx.x * 32, n0 = blockIdx.y * 128;
    int vbase = blockIdx.z * 288;
    float acc[4][4][3];
#pragma unroll
    for (int j = 0; j < 4; ++j)
#pragma unroll
        for (int jj = 0; jj < 4; ++jj)
#pragma unroll
            for (int c = 0; c < 3; ++c) acc[j][jj][c] = 0.f;

    for (int t = 0; t < 9; ++t) {
        int v0 = vbase + t * 32;
        for (int e = tid; e < 32 * 32; e += 256) {
            int kr = e >> 5, vv = e & 31;
            int kg = k0 + kr, vg = v0 + vv;
            float val = 0.f;
            if (kg < NK && vg < V) {
                const float* row = (kg < 25) ? (b25 + (size_t)kg * V)
                                             : (face + (size_t)(kg - 25) * V);
                val = row[vg];
            }
            rs[kr * 36 + vv] = val;
        }
        for (int e = tid; e < 128 * 96; e += 256) {
            int nn = e / 96, rem = e - nn * 96;
            int vv = rem / 3, c = rem - vv * 3;
            int vg = v0 + vv;
            float val = (vg < V) ? ws[VP_OFF + (size_t)(n0 + nn) * V3 + (size_t)vg * 3 + c] : 0.f;
            vs[nn * 108 + c * 36 + vv] = val;
        }
        __syncthreads();
#pragma unroll
        for (int v4 = 0; v4 < 8; ++v4) {
            float4 r[4];
#pragma unroll
            for (int j = 0; j < 4; ++j)
                r[j] = *reinterpret_cast<const float4*>(&rs[(kq + 8 * j) * 36 + v4 * 4]);
#pragma unroll
            for (int jj = 0; jj < 4; ++jj) {
                int nn = nq + 32 * jj;
                const float* vb = &vs[nn * 108 + v4 * 4];
                float4 vx = *reinterpret_cast<const float4*>(vb);
                float4 vy = *reinterpret_cast<const float4*>(vb + 36);
                float4 vz = *reinterpret_cast<const float4*>(vb + 72);
#pragma unroll
                for (int j = 0; j < 4; ++j) {
                    acc[j][jj][0] += r[j].x * vx.x + r[j].y * vx.y + r[j].z * vx.z + r[j].w * vx.w;
                    acc[j][jj][1] += r[j].x * vy.x + r[j].y * vy.y + r[j].z * vy.z + r[j].w * vy.w;
                    acc[j][jj][2] += r[j].x * vz.x + r[j].y * vz.y + r[j].z * vz.z + r[j].w * vz.w;
                }
            }
        }
        __syncthreads();
    }
#pragma unroll
    for (int j = 0; j < 4; ++j) {
        int kg = k0 + kq + 8 * j;
        if (kg >= NK) continue;
#pragma unroll
        for (int jj = 0; jj < 4; ++jj) {
            int ng = n0 + nq + 32 * jj;
#pragma unroll
            for (int c = 0; c < 3; ++c)
                atomicAdd(&out[(size_t)ng * (NK * 3) + kg * 3 + c], acc[j][jj][c]);
        }
    }
}

// ---------------------------------------------------------------------------
extern "C" void kernel_launch(void* const* d_in, const int* in_sizes, int n_in,
                              void* d_out, int out_size, void* d_ws, size_t ws_size,
                              hipStream_t stream) {
    const float* pose  = (const float*)d_in[0];
    const float* betas = (const float*)d_in[1];
    const float* trans = (const float*)d_in[2];
    const float* vt    = (const float*)d_in[3];
    const float* sd    = (const float*)d_in[4];
    const float* jreg  = (const float*)d_in[5];
    const float* pdirs = (const float*)d_in[6];
    const float* lbsw  = (const float*)d_in[7];
    const float* b25   = (const float*)d_in[8];
    const float* face  = (const float*)d_in[9];
    float* ws  = (float*)d_ws;
    float* out = (float*)d_out;

    hipMemsetAsync(d_out, 0, (size_t)out_size * sizeof(float), stream);

    k_pre   <<<72, 256, 0, stream>>>(jreg, sd, vt, ws);
    k_scale <<<2, 256, 0, stream>>>(betas, vt, sd, ws);
    k_joints<<<(N * 72 + 255) / 256, 256, 0, stream>>>(betas, ws);
    k_fk    <<<N, 64, 0, stream>>>(pose, ws);
    k_posegemm<<<dim3(21, 32), 256, 0, stream>>>(pose, betas, vt, sd, pdirs, ws);
    k_lbs   <<<dim3(27, N), 256, 0, stream>>>(lbsw, trans, ws);
    k_reg   <<<dim3(3, 4, 24), 256, 0, stream>>>(b25, face, ws, out);
}

// Round 2
// 509.504 us; speedup vs baseline: 1.4125x; 1.4125x over previous
//
#include <hip/hip_runtime.h>

// SMPL body model forward: fp32 pipeline.
// R1 change: k_reg restructured — 2D register tile (6k x 3c x 1n per thread),
// conflict-free LDS strides, 16-way v-split for parallelism, atomics for partials.

constexpr int N   = 512;
constexpr int V   = 6890;
constexpr int V3  = V * 3;        // 20670
constexpr int NJ  = 24;
constexpr int NB  = 10;
constexpr int NP  = 207;
constexpr int NK  = 95;           // 25 body + 70 face keypoints

// workspace layout (float offsets)
constexpr size_t VP_OFF    = 0;                               // v_posed -> verts (in place), N*V3
constexpr size_t SCALE_OFF = (size_t)N * V3;                  // N
constexpr size_t SJ_OFF    = SCALE_OFF + N;                   // NB*72
constexpr size_t JT_OFF    = SJ_OFF + (size_t)NB * 72;        // 72
constexpr size_t J_OFF     = JT_OFF + 72;                     // N*72
constexpr size_t A_OFF     = J_OFF + (size_t)N * 72;          // N*288 (3x4 rows per joint)

// ---------------------------------------------------------------------------
// SJ[k][j][c] = sum_v shapedirs[k, v*3+c] * Jreg[j,v];  Jt[j][c] = sum_v vt[v*3+c]*Jreg[j,v]
__global__ __launch_bounds__(256) void k_pre(const float* __restrict__ jreg,
                                             const float* __restrict__ sd,
                                             const float* __restrict__ vt,
                                             float* __restrict__ ws) {
    int jc = blockIdx.x;                 // 0..71
    int j = jc / 3, c = jc % 3;
    int tid = threadIdx.x;
    float acc[NB + 1];
#pragma unroll
    for (int t = 0; t <= NB; ++t) acc[t] = 0.f;
    for (int v = tid; v < V; v += 256) {
        float w = jreg[(size_t)j * V + v];
        int col = v * 3 + c;
#pragma unroll
        for (int k = 0; k < NB; ++k) acc[k] += w * sd[(size_t)k * V3 + col];
        acc[NB] += w * vt[col];
    }
    __shared__ float red[256];
    for (int t = 0; t <= NB; ++t) {
        red[tid] = acc[t];
        __syncthreads();
        for (int s = 128; s > 0; s >>= 1) {
            if (tid < s) red[tid] += red[tid + s];
            __syncthreads();
        }
        if (tid == 0) {
            if (t < NB) ws[SJ_OFF + (size_t)t * 72 + jc] = red[0];
            else        ws[JT_OFF + jc] = red[0];
        }
        __syncthreads();
    }
}

// ---------------------------------------------------------------------------
__global__ __launch_bounds__(256) void k_scale(const float* __restrict__ betas,
                                               const float* __restrict__ vt,
                                               const float* __restrict__ sd,
                                               float* __restrict__ ws) {
    int n = blockIdx.x * 256 + threadIdx.x;
    if (n >= N) return;
    const int idx[4] = {2802 * 3 + 1, 6262 * 3 + 1, 2237 * 3 + 1, 6728 * 3 + 1};
    float b[NB];
#pragma unroll
    for (int k = 0; k < NB; ++k) b[k] = betas[n * NB + k];
    float vals[4];
#pragma unroll
    for (int t = 0; t < 4; ++t) {
        float a = vt[idx[t]];
#pragma unroll
        for (int k = 0; k < NB; ++k) a += b[k] * sd[(size_t)k * V3 + idx[t]];
        vals[t] = a;
    }
    float h = vals[0] + vals[1] - vals[2] - vals[3];
    ws[SCALE_OFF + n] = 1.66f / h;
}

// ---------------------------------------------------------------------------
__global__ __launch_bounds__(256) void k_joints(const float* __restrict__ betas,
                                                float* __restrict__ ws) {
    int t = blockIdx.x * 256 + threadIdx.x;
    if (t >= N * 72) return;
    int n = t / 72, jc = t - n * 72;
    float a = ws[JT_OFF + jc];
#pragma unroll
    for (int k = 0; k < NB; ++k) a += betas[n * NB + k] * ws[SJ_OFF + (size_t)k * 72 + jc];
    ws[J_OFF + t] = ws[SCALE_OFF + n] * a;
}

// ---------------------------------------------------------------------------
// FK: one block (1 wave) per batch item.
__global__ __launch_bounds__(64) void k_fk(const float* __restrict__ pose,
                                           float* __restrict__ ws) {
    int n = blockIdx.x;
    int tid = threadIdx.x;
    __shared__ float G[NJ * 12];
    __shared__ float Jl[NJ * 3];
    for (int e = tid; e < 72; e += 64) Jl[e] = ws[J_OFF + (size_t)n * 72 + e];
    __syncthreads();
    const int par[NJ] = {0,0,0,0,1,2,3,4,5,6,7,8,9,9,9,12,13,14,16,17,18,19,20,21};
    if (tid < 12) {
        int r = tid >> 2, c = tid & 3;
        G[tid] = (c < 3) ? pose[(size_t)n * 216 + r * 3 + c] : Jl[r];
    }
    __syncthreads();
    for (int i = 1; i < NJ; ++i) {
        int p = par[i];
        if (tid < 12) {
            int r = tid >> 2, c = tid & 3;
            const float* gp = &G[p * 12 + r * 4];
            float v;
            if (c < 3) {
                const float* Ri = pose + (size_t)n * 216 + i * 9;
                v = gp[0] * Ri[0 * 3 + c] + gp[1] * Ri[1 * 3 + c] + gp[2] * Ri[2 * 3 + c];
            } else {
                float t0 = Jl[i * 3 + 0] - Jl[p * 3 + 0];
                float t1 = Jl[i * 3 + 1] - Jl[p * 3 + 1];
                float t2 = Jl[i * 3 + 2] - Jl[p * 3 + 2];
                v = gp[0] * t0 + gp[1] * t1 + gp[2] * t2 + gp[3];
            }
            G[i * 12 + tid] = v;
        }
        __syncthreads();
    }
    for (int idx = tid; idx < 288; idx += 64) {
        int j = idx / 12, rc = idx - j * 12;
        int r = rc >> 2, c = rc & 3;
        float v;
        if (c < 3) v = G[j * 12 + rc];
        else {
            const float* g = &G[j * 12 + r * 4];
            v = g[3] - (g[0] * Jl[j * 3 + 0] + g[1] * Jl[j * 3 + 1] + g[2] * Jl[j * 3 + 2]);
        }
        ws[A_OFF + (size_t)n * 288 + idx] = v;
    }
}

// ---------------------------------------------------------------------------
// v_posed = pose_feature @ posedirs + scale*(betas@shapedirs + vt)
__global__ __launch_bounds__(256) void k_posegemm(const float* __restrict__ pose,
                                                  const float* __restrict__ betas,
                                                  const float* __restrict__ vt,
                                                  const float* __restrict__ sd,
                                                  const float* __restrict__ pdirs,
                                                  float* __restrict__ ws) {
    __shared__ float pf[16 * 208];
    __shared__ float bs[16 * NB];
    __shared__ float ss[16];
    int tid = threadIdx.x;
    int n0 = blockIdx.y * 16;
    int c0 = blockIdx.x * 1024;
    for (int e = tid; e < 16 * NP; e += 256) {
        int nn = e / NP, k = e - nn * NP;
        float v = pose[(size_t)(n0 + nn) * 216 + 9 + k];
        int km = k % 9;
        if (km == 0 || km == 4 || km == 8) v -= 1.f;
        pf[nn * 208 + k] = v;
    }
    if (tid < 16 * NB) bs[tid] = betas[n0 * NB + tid];
    if (tid < 16) ss[tid] = ws[SCALE_OFF + n0 + tid];
    __syncthreads();

    int col[4];
#pragma unroll
    for (int q = 0; q < 4; ++q) {
        int i = c0 + tid + 256 * q;
        col[q] = (i < V3) ? i : (V3 - 1);
    }
    float acc[16][4];
#pragma unroll
    for (int nn = 0; nn < 16; ++nn)
#pragma unroll
        for (int q = 0; q < 4; ++q) acc[nn][q] = 0.f;

    for (int k4 = 0; k4 < 51; ++k4) {
        float b[4][4];
#pragma unroll
        for (int kk = 0; kk < 4; ++kk) {
            const float* row = pdirs + (size_t)(k4 * 4 + kk) * V3;
#pragma unroll
            for (int q = 0; q < 4; ++q) b[kk][q] = row[col[q]];
        }
#pragma unroll
        for (int nn = 0; nn < 16; ++nn) {
            float4 p = *reinterpret_cast<const float4*>(&pf[nn * 208 + k4 * 4]);
#pragma unroll
            for (int q = 0; q < 4; ++q)
                acc[nn][q] += p.x * b[0][q] + p.y * b[1][q] + p.z * b[2][q] + p.w * b[3][q];
        }
    }
    for (int k = 204; k < NP; ++k) {
        float b[4];
        const float* row = pdirs + (size_t)k * V3;
#pragma unroll
        for (int q = 0; q < 4; ++q) b[q] = row[col[q]];
#pragma unroll
        for (int nn = 0; nn < 16; ++nn) {
            float p = pf[nn * 208 + k];
#pragma unroll
            for (int q = 0; q < 4; ++q) acc[nn][q] += p * b[q];
        }
    }
#pragma unroll
    for (int q = 0; q < 4; ++q) {
        int i = c0 + tid + 256 * q;
        if (i >= V3) continue;
        float sdq[NB];
#pragma unroll
        for (int k = 0; k < NB; ++k) sdq[k] = sd[(size_t)k * V3 + i];
        float vti = vt[i];
        for (int nn = 0; nn < 16; ++nn) {
            float sdot = vti;
#pragma unroll
            for (int k = 0; k < NB; ++k) sdot += bs[nn * NB + k] * sdq[k];
            ws[VP_OFF + (size_t)(n0 + nn) * V3 + i] = acc[nn][q] + ss[nn] * sdot;
        }
    }
}

// ---------------------------------------------------------------------------
// LBS in place over v_posed.
__global__ __launch_bounds__(256) void k_lbs(const float* __restrict__ lbsw,
                                             const float* __restrict__ trans,
                                             float* __restrict__ ws) {
    __shared__ float wl[256 * 25];
    int tid = threadIdx.x;
    int n = blockIdx.y;
    int v0 = blockIdx.x * 256;
    for (int e = tid; e < 256 * 24; e += 256) {
        int g = v0 * 24 + e;
        float val = (g < V * 24) ? lbsw[g] : 0.f;
        int vv = e / 24, j = e - vv * 24;
        wl[vv * 25 + j] = val;
    }
    __syncthreads();
    int v = v0 + tid;
    if (v >= V) return;
    const float* An = ws + A_OFF + (size_t)n * 288;
    size_t vp_idx = VP_OFF + (size_t)n * V3 + (size_t)v * 3;
    float p0 = ws[vp_idx + 0], p1 = ws[vp_idx + 1], p2 = ws[vp_idx + 2];
    float T[12];
#pragma unroll
    for (int e = 0; e < 12; ++e) T[e] = 0.f;
    for (int j = 0; j < NJ; ++j) {
        float w = wl[tid * 25 + j];
#pragma unroll
        for (int e = 0; e < 12; ++e) T[e] += w * An[j * 12 + e];
    }
    float x = T[0] * p0 + T[1] * p1 + T[2]  * p2 + T[3]  + trans[n * 3 + 0];
    float y = T[4] * p0 + T[5] * p1 + T[6]  * p2 + T[7]  + trans[n * 3 + 1];
    float z = T[8] * p0 + T[9] * p1 + T[10] * p2 + T[11] + trans[n * 3 + 2];
    ws[vp_idx + 0] = x;
    ws[vp_idx + 1] = y;
    ws[vp_idx + 2] = z;
}

// ---------------------------------------------------------------------------
// R1: out[n,k,c] = sum_v reg[k,v] * verts[n,v,c]
// Block: 256 thr = (tk 0..15) x (tn 0..15). Thread: 6 k (tk+16*jk), 3 c, 1 n.
// LDS: rs[96 k][64 v] stride 68; vs[16 n][3 c][64 v] stride 68. 39 KB.
// Grid: (16 v-splits, 32 n-groups). Partials atomicAdd'ed into out.
constexpr int VCH = 64;                      // v per chunk
constexpr int NCHUNK = (V + VCH - 1) / VCH;  // 108
__global__ __launch_bounds__(256) void k_reg(const float* __restrict__ b25,
                                             const float* __restrict__ face,
                                             const float* __restrict__ ws,
                                             float* __restrict__ out) {
    __shared__ float rs[96 * 68];
    __shared__ float vs[16 * 3 * 68];
    int tid = threadIdx.x;
    int tk = tid & 15, tn = tid >> 4;
    int n0 = blockIdx.y * 16;
    int zz = blockIdx.x;                     // v-split 0..15

    float acc[6][3];
#pragma unroll
    for (int jk = 0; jk < 6; ++jk)
#pragma unroll
        for (int c = 0; c < 3; ++c) acc[jk][c] = 0.f;

    for (int ch = zz; ch < NCHUNK; ch += 16) {
        int v0 = ch * VCH;
        // stage reg rows [96 x 64]
        for (int e = tid; e < 96 * VCH; e += 256) {
            int kr = e >> 6, vv = e & 63;
            int vg = v0 + vv;
            float val = 0.f;
            if (kr < NK && vg < V) {
                const float* row = (kr < 25) ? (b25 + (size_t)kr * V)
                                             : (face + (size_t)(kr - 25) * V);
                val = row[vg];
            }
            rs[kr * 68 + vv] = val;
        }
        // stage verts [16 n][3 c][64 v]
        for (int e = tid; e < 16 * 3 * VCH; e += 256) {
            int nn = e / 192, rem = e - nn * 192;
            int vv = rem / 3, c = rem - vv * 3;
            int vg = v0 + vv;
            float val = (vg < V) ? ws[VP_OFF + (size_t)(n0 + nn) * V3 + (size_t)vg * 3 + c] : 0.f;
            vs[nn * 204 + c * 68 + vv] = val;
        }
        __syncthreads();
#pragma unroll
        for (int v4 = 0; v4 < VCH / 4; ++v4) {
            float4 r[6];
#pragma unroll
            for (int jk = 0; jk < 6; ++jk)
                r[jk] = *reinterpret_cast<const float4*>(&rs[(tk + 16 * jk) * 68 + v4 * 4]);
            const float* vb = &vs[tn * 204 + v4 * 4];
            float4 vx = *reinterpret_cast<const float4*>(vb);
            float4 vy = *reinterpret_cast<const float4*>(vb + 68);
            float4 vz = *reinterpret_cast<const float4*>(vb + 136);
#pragma unroll
            for (int jk = 0; jk < 6; ++jk) {
                acc[jk][0] += r[jk].x * vx.x + r[jk].y * vx.y + r[jk].z * vx.z + r[jk].w * vx.w;
                acc[jk][1] += r[jk].x * vy.x + r[jk].y * vy.y + r[jk].z * vy.z + r[jk].w * vy.w;
                acc[jk][2] += r[jk].x * vz.x + r[jk].y * vz.y + r[jk].z * vz.z + r[jk].w * vz.w;
            }
        }
        __syncthreads();
    }
    int ng = n0 + tn;
#pragma unroll
    for (int jk = 0; jk < 6; ++jk) {
        int kg = tk + 16 * jk;
        if (kg >= NK) continue;
#pragma unroll
        for (int c = 0; c < 3; ++c)
            atomicAdd(&out[(size_t)ng * (NK * 3) + kg * 3 + c], acc[jk][c]);
    }
}

// ---------------------------------------------------------------------------
extern "C" void kernel_launch(void* const* d_in, const int* in_sizes, int n_in,
                              void* d_out, int out_size, void* d_ws, size_t ws_size,
                              hipStream_t stream) {
    const float* pose  = (const float*)d_in[0];
    const float* betas = (const float*)d_in[1];
    const float* trans = (const float*)d_in[2];
    const float* vt    = (const float*)d_in[3];
    const float* sd    = (const float*)d_in[4];
    const float* jreg  = (const float*)d_in[5];
    const float* pdirs = (const float*)d_in[6];
    const float* lbsw  = (const float*)d_in[7];
    const float* b25   = (const float*)d_in[8];
    const float* face  = (const float*)d_in[9];
    float* ws  = (float*)d_ws;
    float* out = (float*)d_out;

    hipMemsetAsync(d_out, 0, (size_t)out_size * sizeof(float), stream);

    k_pre   <<<72, 256, 0, stream>>>(jreg, sd, vt, ws);
    k_scale <<<2, 256, 0, stream>>>(betas, vt, sd, ws);
    k_joints<<<(N * 72 + 255) / 256, 256, 0, stream>>>(betas, ws);
    k_fk    <<<N, 64, 0, stream>>>(pose, ws);
    k_posegemm<<<dim3(21, 32), 256, 0, stream>>>(pose, betas, vt, sd, pdirs, ws);
    k_lbs   <<<dim3(27, N), 256, 0, stream>>>(lbsw, trans, ws);
    k_reg   <<<dim3(16, 32), 256, 0, stream>>>(b25, face, ws, out);
}